// Round 8
// baseline (341.366 us; speedup 1.0000x reference)
//
#include <hip/hip_runtime.h>

#define Hh 16
#define Nn 8192
#define Dd 64
#define NB 128

typedef float  f32x4   __attribute__((ext_vector_type(4)));
typedef float  f32x16  __attribute__((ext_vector_type(16)));
typedef float  float4_ __attribute__((ext_vector_type(4)));
typedef short  bf16x8  __attribute__((ext_vector_type(8)));
typedef unsigned short ushort8  __attribute__((ext_vector_type(8)));
typedef unsigned short ushort4_ __attribute__((ext_vector_type(4)));

typedef const __attribute__((address_space(1))) unsigned int gu32;
typedef __attribute__((address_space(3))) unsigned int lu32;

// log2(e) / sqrt(64) — folded into Q so QK^T lands in log2 domain
#define QSCALE 0.1803368801111244f

__device__ __forceinline__ unsigned short f2bf(float f) {
    union { float f; unsigned u; } x; x.f = f;
    unsigned r = x.u + 0x7fffu + ((x.u >> 16) & 1u);  // RNE
    return (unsigned short)(r >> 16);
}

__device__ __forceinline__ unsigned pack2bf(float lo, float hi) {
    return (unsigned)f2bf(lo) | ((unsigned)f2bf(hi) << 16);
}

// ---- pre-pass 1: k -> bf16
__global__ void cvt_k(const float* __restrict__ k, unsigned short* __restrict__ ko) {
    int i = blockIdx.x * 256 + threadIdx.x;
    float4_ b = ((const float4_*)k)[i];
    ushort4_ ob;
#pragma unroll
    for (int j = 0; j < 4; ++j) ob[j] = f2bf(b[j]);
    ((ushort4_*)ko)[i] = ob;
}

// ---- pre-pass 2: v -> vt[h][d][n] bf16 (per-head transpose)
__global__ void cvt_vt(const float* __restrict__ v, unsigned short* __restrict__ vt) {
    int jb = blockIdx.x, h = blockIdx.y, t = threadIdx.x;
    __shared__ float T[64][65];
    const float4_* src = (const float4_*)(v + ((long)h * Nn + jb * 64) * Dd);
#pragma unroll
    for (int it = 0; it < 4; ++it) {
        int r = (t >> 4) + it * 16;
        int c0 = (t & 15) * 4;
        float4_ x = src[r * 16 + (t & 15)];
#pragma unroll
        for (int i2 = 0; i2 < 4; ++i2) T[c0 + i2][r] = x[i2];
    }
    __syncthreads();
    int d = t >> 2, seg = (t & 3) * 16;
    ushort8 o0, o1;
#pragma unroll
    for (int i2 = 0; i2 < 8; ++i2) o0[i2] = f2bf(T[d][seg + i2]);
#pragma unroll
    for (int i2 = 0; i2 < 8; ++i2) o1[i2] = f2bf(T[d][seg + 8 + i2]);
    unsigned short* dst = vt + ((long)h * Dd + d) * Nn + jb * 64 + seg;
    *(ushort8*)dst = o0;
    *(ushort8*)(dst + 8) = o1;
}

// =====================================================================
// Main: 256 threads = 4 waves; block = 64 queries (ONE mask row) ->
// fully uniform own-only iteration (no union waste, no masking).
// Split-K: wave (qh=wid&1, kh=wid>>1) computes the 32-query x 32-key
// quadrant: 4 QK MFMA + 16 exp2 + 4 PV MFMA + 2 ls MFMA per iter —
// exactly the round-5/7-proven s0 code path. Partial O/l per key half
// are combined once after the loop via the retired K/V LDS space.
// K/V staged via global_load_lds into fragment-major LDS (4 frags per
// wave), double-buffered with __syncthreads().
// =====================================================================
__global__ __launch_bounds__(256, 4) void attn32(
        const unsigned short* __restrict__ k16,
        const unsigned short* __restrict__ vt16,
        const float* __restrict__ qf,
        const int* __restrict__ mask,
        float* __restrict__ out) {
    int bid = blockIdx.x;
    // head-per-XCD mapping: bid%8 == XCD; heads 0-7 for bid<1024, 8-15 after.
    int h = (bid & 7) | ((bid >> 10) << 3);
    int qb = (bid >> 3) & 127;
    int tid = threadIdx.x;
    int wid = tid >> 6, l = tid & 63;
    int q5 = l & 31, hi = l >> 5;
    int qh = wid & 1;                        // query half (compute role)
    int kh = wid >> 1;                       // key half   (compute role)
    int stage_kv = wid >> 1;                 // waves 0,1 stage K; 2,3 stage V
    int stage_half = wid & 1;                // which 4 fragments

    // Kl: bytes [0,16384)  = [buf][frag 0..7][lane*16]
    // Vl: bytes [16384,32768) same; comb aliases [0,16896) after the loop.
    __shared__ __align__(16) char smem[32768];

    const int* mrow = mask + qb * NB;
    unsigned long long b0 = __ballot(mrow[l] != 0);
    unsigned long long b1 = __ballot(mrow[64 + l] != 0);
    int count = __popcll(b0) + __popcll(b1);

    if (count == 0) {
        float4_ z = {0.f, 0.f, 0.f, 0.f};
        float4_* ob = (float4_*)(out + ((size_t)h * Nn + qb * 64) * Dd);
        for (int x = tid; x < 64 * 64 / 4; x += 256) ob[x] = z;
        return;
    }

    // ---- Q fragments (B-operand: col=q5, k=hi*8+i within d-slice), scale folded
    size_t qrow = (size_t)h * Nn + qb * 64 + qh * 32 + q5;
    bf16x8 qfrag[4];
#pragma unroll
    for (int ds_ = 0; ds_ < 4; ++ds_) {
        const float4_* qs = (const float4_*)(qf + qrow * Dd + ds_ * 16 + hi * 8);
        float4_ x = qs[0], y = qs[1];
        union { unsigned short s[8]; bf16x8 v; } u;
#pragma unroll
        for (int i2 = 0; i2 < 4; ++i2) {
            u.s[i2]     = f2bf(x[i2] * QSCALE);
            u.s[4 + i2] = f2bf(y[i2] * QSCALE);
        }
        qfrag[ds_] = u.v;
    }

    // ---- ones A-fragment for the l-sum MFMA (layout-proof: A==1 => D=colsum(B))
    union { unsigned short s[8]; bf16x8 v; } ones;
#pragma unroll
    for (int i2 = 0; i2 < 8; ++i2) ones.s[i2] = 0x3F80;  // bf16 1.0

    // ---- staging source pointers: this wave's 4 fragments
    // K frag f: key (q5+32*(f>>2)), d-slice (f&3);  V^T frag f: d (q5+32*(f>>2)), key-slice (f&3)
    const unsigned short* sp[4];
    size_t jmul;
#pragma unroll
    for (int ff = 0; ff < 4; ++ff) {
        int f = stage_half * 4 + ff;
        if (stage_kv == 0)
            sp[ff] = k16 + (size_t)h * (Nn * Dd)
                   + (size_t)(q5 + 32 * (f >> 2)) * Dd + (f & 3) * 16 + hi * 8;
        else
            sp[ff] = vt16 + (size_t)h * (Nn * Dd)
                   + (size_t)(q5 + 32 * (f >> 2)) * Nn + (f & 3) * 16 + hi * 8;
    }
    jmul = (stage_kv == 0) ? (size_t)(64 * Dd) : (size_t)64;

    unsigned long long r0 = b0, r1 = b1;
    auto next_j = [&]() {
        int jj;
        if (r0) { jj = __ffsll(r0) - 1; r0 &= r0 - 1; }
        else    { jj = 63 + __ffsll(r1); r1 &= r1 - 1; }
        return jj;
    };

    auto issue = [&](int nbuf, int jj) {
        char* base = smem + (stage_kv ? 16384 : 0) + nbuf * 8192;
#pragma unroll
        for (int ff = 0; ff < 4; ++ff) {
            const unsigned short* g = sp[ff] + (size_t)jj * jmul;
            __builtin_amdgcn_global_load_lds((gu32*)g,
                (lu32*)(base + (stage_half * 4 + ff) * 1024), 16, 0, 0);
        }
    };

    issue(0, next_j());

    f32x16 o0 = {}, o1 = {}, ls = {};

    for (int i = 0; i < count; ++i) {
        int buf = i & 1;
        __syncthreads();                       // drains prefetch + orders buffer reuse
        if (i + 1 < count) issue(buf ^ 1, next_j());   // flies under compute below

        const char* kb = smem + buf * 8192 + kh * 4096 + l * 16;
        const char* vb = smem + 16384 + buf * 8192 + l * 16;

        // ---- QK^T quadrant: S^T[key(kh half)][q] in log2 domain
        f32x16 s = {};
#pragma unroll
        for (int ds_ = 0; ds_ < 4; ++ds_) {
            bf16x8 kf = *(const bf16x8*)(kb + ds_ * 1024);
            s = __builtin_amdgcn_mfma_f32_32x32x16_bf16(kf, qfrag[ds_], s, 0, 0, 0);
        }

        // ---- P = 2^S (compiler-emitted v_exp_f32; hazard-safe)
#pragma unroll
        for (int e = 0; e < 16; ++e) s[e] = __builtin_amdgcn_exp2f(s[e]);

        // ---- P -> bf16 B-fragments in registers (pack pairs, half-wave exchange)
        unsigned w[8];
#pragma unroll
        for (int jj = 0; jj < 8; ++jj) w[jj] = pack2bf(s[2 * jj], s[2 * jj + 1]);
        auto swap32 = [&](unsigned& a, unsigned& b) {
            unsigned send = hi ? a : b;
            unsigned recv = (unsigned)__shfl_xor((int)send, 32);
            a = hi ? recv : a;
            b = hi ? b : recv;
        };
        swap32(w[0], w[2]); swap32(w[1], w[3]);
        swap32(w[4], w[6]); swap32(w[5], w[7]);

        union U { unsigned u[4]; bf16x8 v; };
        U pbs[2];
        pbs[0].u[0] = w[0]; pbs[0].u[1] = w[1]; pbs[0].u[2] = w[2]; pbs[0].u[3] = w[3];
        pbs[1].u[0] = w[4]; pbs[1].u[1] = w[5]; pbs[1].u[2] = w[6]; pbs[1].u[3] = w[7];

        // ---- PV quadrant: O^T[d][q] += V^T-frag x P-frag (key slices kh*2, kh*2+1)
        int c0 = kh * 2;
#pragma unroll
        for (int sl = 0; sl < 2; ++sl) {
            bf16x8 vf0 = *(const bf16x8*)(vb + (c0 + sl) * 1024);
            o0 = __builtin_amdgcn_mfma_f32_32x32x16_bf16(vf0, pbs[sl].v, o0, 0, 0, 0);
        }
#pragma unroll
        for (int sl = 0; sl < 2; ++sl) {
            bf16x8 vf1 = *(const bf16x8*)(vb + 4096 + (c0 + sl) * 1024);
            o1 = __builtin_amdgcn_mfma_f32_32x32x16_bf16(vf1, pbs[sl].v, o1, 0, 0, 0);
        }
        // ---- partial l on the MFMA pipe
        ls = __builtin_amdgcn_mfma_f32_32x32x16_bf16(ones.v, pbs[0].v, ls, 0, 0, 0);
        ls = __builtin_amdgcn_mfma_f32_32x32x16_bf16(ones.v, pbs[1].v, ls, 0, 0, 0);
    }

    // ---- cross-wave combine: kh=1 partials -> kh=0 via retired LDS
    __syncthreads();                           // all LDS reads of K/V done
    float* comb = (float*)smem;                // [2 qh][64 lane][33]
    if (kh == 1) {
        float* dst = comb + (qh * 64 + l) * 33;
#pragma unroll
        for (int e = 0; e < 16; ++e) { dst[e] = o0[e]; dst[16 + e] = o1[e]; }
        dst[32] = ls[0];
    }
    __syncthreads();
    if (kh == 0) {
        const float* src = comb + (qh * 64 + l) * 33;
#pragma unroll
        for (int e = 0; e < 16; ++e) { o0[e] += src[e]; o1[e] += src[16 + e]; }
        float inv = 1.0f / (ls[0] + src[32]);

        // epilogue: O[q][d] = O^T/l, d = chunk*32 + 8*s4 + 4*hi + e
        float* obase = out + qrow * Dd;
#pragma unroll
        for (int s4 = 0; s4 < 4; ++s4) {
            float4_ t0, t1;
#pragma unroll
            for (int e = 0; e < 4; ++e) { t0[e] = o0[4 * s4 + e] * inv; t1[e] = o1[4 * s4 + e] * inv; }
            *(float4_*)(obase + 8 * s4 + 4 * hi)      = t0;
            *(float4_*)(obase + 32 + 8 * s4 + 4 * hi) = t1;
        }
    }
}

// =====================================================================
// Fallback (ws too small): round-1 proven fp32-input kernel
// =====================================================================
__global__ void attn_main(const float* __restrict__ qf, const float* __restrict__ kf,
                          const float* __restrict__ vf, const int* __restrict__ mask,
                          float* __restrict__ out) {
    int id = blockIdx.x;
    int h = id & 15, qb = id >> 4;
    int tid = threadIdx.x;
    int lane = tid & 63, wid = tid >> 6;
    int l15 = lane & 15, l4 = lane >> 4;

    __shared__ unsigned short Kl[2][64 * 64];
    __shared__ unsigned short Vl[2][64 * 64];
    __shared__ unsigned short Pl[4][16 * 64];

    const int* mrow = mask + qb * NB;
    unsigned long long b0 = __ballot(mrow[lane] != 0);
    unsigned long long b1 = __ballot(mrow[64 + lane] != 0);
    int count = __popcll(b0) + __popcll(b1);

    float* op = out + ((long)h * Nn + qb * 64 + wid * 16) * Dd;

    if (count == 0) {
#pragma unroll
        for (int r = 0; r < 4; ++r)
#pragma unroll
            for (int dn = 0; dn < 4; ++dn)
                op[(l4 * 4 + r) * Dd + dn * 16 + l15] = 0.f;
        return;
    }

    long qrow = (long)h * Nn + qb * 64 + wid * 16 + l15;
    bf16x8 qfrag[2];
#pragma unroll
    for (int dc = 0; dc < 2; ++dc) {
        const float4_* qs = (const float4_*)qf + qrow * 16 + dc * 8 + l4 * 2;
        float4_ x = qs[0], y = qs[1];
        union { unsigned short s[8]; bf16x8 v; } u;
#pragma unroll
        for (int i2 = 0; i2 < 4; ++i2) {
            u.s[i2] = f2bf(x[i2] * 0.125f);
            u.s[4 + i2] = f2bf(y[i2] * 0.125f);
        }
        qfrag[dc] = u.v;
    }

    int sgq = tid & 7;
    int srow = tid >> 3;
    float4_ kf4[2][2]; float4_ vf4[4];
    int vk = tid & 63, vd0 = (tid >> 6) * 16;

    auto load_kv = [&](int j) {
        const float4_* ks = (const float4_*)kf + ((long)h * Nn + j * 64) * 16;
#pragma unroll
        for (int it = 0; it < 2; ++it) {
            kf4[it][0] = ks[(srow + it * 32) * 16 + sgq * 2];
            kf4[it][1] = ks[(srow + it * 32) * 16 + sgq * 2 + 1];
        }
        const float4_* vs = (const float4_*)vf + ((long)h * Nn + j * 64) * 16;
#pragma unroll
        for (int c = 0; c < 4; ++c) vf4[c] = vs[vk * 16 + (vd0 >> 2) + c];
    };

    auto write_kv = [&](int buf) {
#pragma unroll
        for (int it = 0; it < 2; ++it) {
            int r = srow + it * 32;
            union { unsigned short s[8]; ushort8 v; } u;
#pragma unroll
            for (int i2 = 0; i2 < 4; ++i2) {
                u.s[i2] = f2bf(kf4[it][0][i2]);
                u.s[4 + i2] = f2bf(kf4[it][1][i2]);
            }
            *(ushort8*)((char*)&Kl[buf][0] + r * 128 + (((sgq ^ r) & 7) << 4)) = u.v;
        }
#pragma unroll
        for (int i2 = 0; i2 < 16; ++i2) {
            int d = vd0 + i2;
            *((unsigned short*)((char*)&Vl[buf][0] + d * 128 +
                ((((vk >> 3) ^ d) & 7) << 4) + ((vk & 7) << 1))) = f2bf(vf4[i2 >> 2][i2 & 3]);
        }
    };

    f32x4 o_acc[4] = {};
    float m_r[4], l_r[4];
#pragma unroll
    for (int r = 0; r < 4; ++r) { m_r[r] = -INFINITY; l_r[r] = 0.f; }

    unsigned long long r0 = b0, r1 = b1;
    auto next_j = [&]() {
        int jj;
        if (r0) { jj = __ffsll(r0) - 1; r0 &= r0 - 1; }
        else    { jj = 63 + __ffsll(r1); r1 &= r1 - 1; }
        return jj;
    };

    load_kv(next_j());

    for (int i = 0; i < count; ++i) {
        int buf = i & 1;
        write_kv(buf);
        __syncthreads();
        if (i + 1 < count) load_kv(next_j());

        f32x4 s[4] = {};
#pragma unroll
        for (int dc = 0; dc < 2; ++dc) {
#pragma unroll
            for (int kn = 0; kn < 4; ++kn) {
                int krow = kn * 16 + l15;
                bf16x8 kfr = *(const bf16x8*)((const char*)&Kl[buf][0] +
                               krow * 128 + ((((l4 + dc * 4) ^ krow) & 7) << 4));
                s[kn] = __builtin_amdgcn_mfma_f32_16x16x32_bf16(qfrag[dc], kfr, s[kn], 0, 0, 0);
            }
        }

#pragma unroll
        for (int r = 0; r < 4; ++r) {
            float mx = fmaxf(fmaxf(s[0][r], s[1][r]), fmaxf(s[2][r], s[3][r]));
#pragma unroll
            for (int off = 1; off < 16; off <<= 1) mx = fmaxf(mx, __shfl_xor(mx, off));
            float mn = fmaxf(m_r[r], mx);
            float a = __expf(m_r[r] - mn);
            m_r[r] = mn;
            float psum = 0.f;
#pragma unroll
            for (int kn = 0; kn < 4; ++kn) { float p = __expf(s[kn][r] - mn); s[kn][r] = p; psum += p; }
#pragma unroll
            for (int off = 1; off < 16; off <<= 1) psum += __shfl_xor(psum, off);
            l_r[r] = l_r[r] * a + psum;
            o_acc[0][r] *= a; o_acc[1][r] *= a; o_acc[2][r] *= a; o_acc[3][r] *= a;
        }

#pragma unroll
        for (int kn = 0; kn < 4; ++kn) {
#pragma unroll
            for (int r = 0; r < 4; ++r) {
                int prow = l4 * 4 + r;
                int pc = kn * 16 + l15;
                *((unsigned short*)((char*)&Pl[wid][0] + prow * 128 +
                    ((((pc >> 3) ^ prow) & 7) << 4) + ((pc & 7) << 1))) = f2bf(s[kn][r]);
            }
        }

        bf16x8 pa[2];
#pragma unroll
        for (int kc = 0; kc < 2; ++kc)
            pa[kc] = *(const bf16x8*)((const char*)&Pl[wid][0] +
                      l15 * 128 + ((((l4 + kc * 4) ^ l15) & 7) << 4));
#pragma unroll
        for (int dn = 0; dn < 4; ++dn) {
            int vrow = dn * 16 + l15;
#pragma unroll
            for (int kc = 0; kc < 2; ++kc) {
                bf16x8 vbf = *(const bf16x8*)((const char*)&Vl[buf][0] +
                             vrow * 128 + ((((l4 + kc * 4) ^ vrow) & 7) << 4));
                o_acc[dn] = __builtin_amdgcn_mfma_f32_16x16x32_bf16(pa[kc], vbf, o_acc[dn], 0, 0, 0);
            }
        }
    }

#pragma unroll
    for (int r = 0; r < 4; ++r) {
        float inv = 1.0f / l_r[r];
#pragma unroll
        for (int dn = 0; dn < 4; ++dn)
            op[(l4 * 4 + r) * Dd + dn * 16 + l15] = o_acc[dn][r] * inv;
    }
}

extern "C" void kernel_launch(void* const* d_in, const int* in_sizes, int n_in,
                              void* d_out, int out_size, void* d_ws, size_t ws_size,
                              hipStream_t stream) {
    const float* q = (const float*)d_in[0];
    const float* k = (const float*)d_in[1];
    const float* v = (const float*)d_in[2];
    const int* mask = (const int*)d_in[3];
    float* out = (float*)d_out;

    size_t elems = (size_t)Hh * Nn * Dd;
    size_t need = 2 * elems * sizeof(unsigned short);   // 32 MB (k16 + vt16)
    if (ws_size >= need) {
        unsigned short* k16 = (unsigned short*)d_ws;
        unsigned short* vt16 = k16 + elems;
        cvt_k<<<dim3((unsigned)(elems / 1024)), 256, 0, stream>>>(k, k16);
        cvt_vt<<<dim3(NB, Hh), 256, 0, stream>>>(v, vt16);
        attn32<<<dim3(Hh * NB), 256, 0, stream>>>(k16, vt16, q, mask, out);
    } else {
        attn_main<<<dim3(Hh * NB), 256, 0, stream>>>(q, k, v, mask, out);
    }
}